// Round 8
// baseline (280.997 us; speedup 1.0000x reference)
//
#include <hip/hip_runtime.h>

#define DEV __device__ __forceinline__

typedef __bf16 bf16x8 __attribute__((ext_vector_type(8)));
typedef float  f32x4  __attribute__((ext_vector_type(4)));

// ---- constants ----
constexpr int B_ = 4, S_ = 2048, D_ = 1024;
constexpr int NTOK = B_ * S_;               // 8192
constexpr size_t XB_ELEMS = (size_t)NTOK * D_;        // 8,388,608
constexpr size_t WB_ELEMS = (size_t)3 * D_ * D_;      // 3,145,728
constexpr size_t OFF_XB = 0;
constexpr size_t OFF_WB = OFF_XB + XB_ELEMS * 2;      // 16,777,216
constexpr size_t OFF_QB = OFF_WB + WB_ELEMS * 2;      // 23,068,672
constexpr size_t OFF_KB = OFF_QB + XB_ELEMS * 2;
constexpr size_t OFF_VB = OFF_KB + XB_ELEMS * 2;
constexpr size_t OFF_SB = OFF_VB + XB_ELEMS * 2;      // 73,400,320 (fp32 scores, 67MB)
// P dense bf16 [B][S][S] = 33,554,432 B reuses qb+kb (dead after scores) at OFF_QB.

DEV unsigned short f2bf(float f) {            // RNE float->bf16
  unsigned u = __float_as_uint(f);
  u += 0x7fffu + ((u >> 16) & 1u);
  return (unsigned short)(u >> 16);
}

DEV void gload16(const void* g, void* l) {    // 16B global->LDS direct
  __builtin_amdgcn_global_load_lds(
      (const __attribute__((address_space(1))) void*)g,
      (__attribute__((address_space(3))) void*)l, 16, 0, 0);
}

// ---------------- fused cast fp32 -> bf16 (x, wq, wk, wv in one launch) ----------------
__global__ __launch_bounds__(256) void cast_all(const float* __restrict__ x,
                                                const float* __restrict__ wq,
                                                const float* __restrict__ wk,
                                                const float* __restrict__ wv,
                                                unsigned short* __restrict__ xb,
                                                unsigned short* __restrict__ wb) {
  constexpr int NX4 = (int)(XB_ELEMS / 4);    // 2,097,152
  constexpr int NW4 = D_ * D_ / 4;            // 262,144
  constexpr int NT4 = NX4 + 3 * NW4;
  int i = blockIdx.x * 256 + threadIdx.x;
  const int stride = gridDim.x * 256;
  for (; i < NT4; i += stride) {
    const float4* s;
    ushort4* d;
    if (i < NX4) {
      s = (const float4*)x + i;
      d = (ushort4*)xb + i;
    } else {
      int j = i - NX4;
      int seg = j / NW4;
      int off = j - seg * NW4;
      const float* w = seg == 0 ? wq : (seg == 1 ? wk : wv);
      s = (const float4*)w + off;
      d = (ushort4*)wb + (size_t)seg * NW4 + off;
    }
    float4 v = *s;
    ushort4 o;
    o.x = f2bf(v.x); o.y = f2bf(v.y); o.z = f2bf(v.z); o.w = f2bf(v.w);
    *d = o;
  }
}

// ================= 8-phase 256x128 GEMM (T2+T3+T4+T5), QKV =================
// Grid 32x24 = 768 blocks = exactly 3 full rounds on 256 CUs (tail-free).
// (Measured r6: 67.1us, 0 bank conflicts. At the NT=16 phase-density plateau.)
__global__ __launch_bounds__(512, 2) void qkv_gemm8(
    const unsigned short* __restrict__ xb, const unsigned short* __restrict__ wb,
    const float* __restrict__ bq, const float* __restrict__ bk, const float* __restrict__ bv,
    unsigned short* __restrict__ qb, unsigned short* __restrict__ kb, unsigned short* __restrict__ vb) {
  __shared__ unsigned short lds8[49152];      // 98,304 B
  const int tid  = threadIdx.x;
  const int lane = tid & 63, wid = tid >> 6;
  const int wm = wid >> 2, wn = wid & 3;
  const int mt = blockIdx.x, nt = blockIdx.y;
  const int arow0 = mt * 256, brow0 = nt * 128;
  const int fr = lane & 15;
  const int fk16 = (lane >> 4) * 16;          // byte offset of k-chunk within 128B row
  const int srow = tid >> 3;                  // 0..63
  const int scol = (((tid & 7) * 16) ^ ((srow & 7) << 4)) >> 1;  // pre-swizzled src col

  f32x4 acc[8][2];
#pragma unroll
  for (int i = 0; i < 8; ++i)
#pragma unroll
    for (int j = 0; j < 2; ++j) { f32x4 z = {0.f, 0.f, 0.f, 0.f}; acc[i][j] = z; }

  auto stageA = [&](int buf, int T, int h) {  // half h = 128 rows of A K-tile T (2 loads)
    unsigned short* d = lds8 + buf * 24576 + h * 8192 + tid * 8;
    const unsigned short* s = xb + (size_t)(arow0 + h * 128 + srow) * D_ + T * 64 + scol;
    gload16(s, d);
    gload16(s + (size_t)64 * D_, d + 4096);
  };
  auto stageB = [&](int buf, int T, int h) {  // half h = 64 rows of B K-tile T (1 load)
    unsigned short* d = lds8 + buf * 24576 + 16384 + h * 4096 + tid * 8;
    const unsigned short* s = wb + (size_t)(brow0 + h * 64 + srow) * D_ + T * 64 + scol;
    gload16(s, d);
  };
  auto ldA = [&](int buf, int mh, int m2, int kk) -> bf16x8 {
    int row = wm * 128 + mh * 64 + m2 * 16 + fr;
    int cb = (kk * 64 + fk16) ^ ((row & 7) << 4);
    return *(const bf16x8*)(lds8 + buf * 24576 + row * 64 + (cb >> 1));
  };
  auto ldB = [&](int buf, int nh, int kk) -> bf16x8 {
    int row = wn * 32 + nh * 16 + fr;
    int cb = (kk * 64 + fk16) ^ ((row & 7) << 4);
    return *(const bf16x8*)(lds8 + buf * 24576 + 16384 + row * 64 + (cb >> 1));
  };

#define MFMA_QUAD(MH, NH, BFR)                                                     \
  do {                                                                             \
    __builtin_amdgcn_s_setprio(1);                                                 \
    _Pragma("unroll") for (int m2 = 0; m2 < 4; ++m2)                               \
    _Pragma("unroll") for (int kk = 0; kk < 2; ++kk)                               \
      acc[(MH) * 4 + m2][(NH)] = __builtin_amdgcn_mfma_f32_16x16x32_bf16(          \
          afr[m2][kk], BFR[kk], acc[(MH) * 4 + m2][(NH)], 0, 0, 0);                \
    __builtin_amdgcn_s_setprio(0);                                                 \
  } while (0)

  constexpr int NT = 16;                      // K=1024 / 64
  stageB(0, 0, 0); stageB(0, 0, 1);
  stageA(0, 0, 0); stageA(0, 0, 1);
  stageB(1, 1, 0); stageB(1, 1, 1);
  asm volatile("s_waitcnt vmcnt(2)" ::: "memory");
  __builtin_amdgcn_s_barrier();

  bf16x8 afr[4][2], bfr0[2], bfr1[2];
#pragma unroll 2
  for (int T = 0; T < NT; ++T) {
    const int cur = T & 1, nxt = cur ^ 1;
    // ---- P1 ----
#pragma unroll
    for (int kk = 0; kk < 2; ++kk) bfr0[kk] = ldB(cur, 0, kk);
#pragma unroll
    for (int m2 = 0; m2 < 4; ++m2)
#pragma unroll
      for (int kk = 0; kk < 2; ++kk) afr[m2][kk] = ldA(cur, 0, m2, kk);
    if (T + 1 < NT) stageA(nxt, T + 1, 0);
    __builtin_amdgcn_s_barrier();
    MFMA_QUAD(0, 0, bfr0);
    __builtin_amdgcn_s_barrier();
    // ---- P2 ----
#pragma unroll
    for (int kk = 0; kk < 2; ++kk) bfr1[kk] = ldB(cur, 1, kk);
    if (T + 1 < NT) stageA(nxt, T + 1, 1);
    __builtin_amdgcn_s_barrier();
    MFMA_QUAD(0, 1, bfr1);
    __builtin_amdgcn_s_barrier();
    // ---- P3 ----
#pragma unroll
    for (int m2 = 0; m2 < 4; ++m2)
#pragma unroll
      for (int kk = 0; kk < 2; ++kk) afr[m2][kk] = ldA(cur, 1, m2, kk);
    if (T + 2 < NT) stageB(cur, T + 2, 0);
    __builtin_amdgcn_s_barrier();
    MFMA_QUAD(1, 0, bfr0);
    __builtin_amdgcn_s_barrier();
    // ---- P4 ----
    if (T + 2 < NT) stageB(cur, T + 2, 1);
    __builtin_amdgcn_s_barrier();
    MFMA_QUAD(1, 1, bfr1);
    if (T + 2 < NT) {
      asm volatile("s_waitcnt vmcnt(2)" ::: "memory");
    } else {
      asm volatile("s_waitcnt vmcnt(0)" ::: "memory");
    }
    __builtin_amdgcn_s_barrier();
  }
#undef MFMA_QUAD

  // epilogue: bias + bf16 store. nt in [0,24): proj = nt/8, col tile = nt%8.
  const int proj  = nt >> 3;
  const int ncol0 = (nt & 7) * 128;
  unsigned short* dst  = proj == 0 ? qb : (proj == 1 ? kb : vb);
  const float*    bias = proj == 0 ? bq : (proj == 1 ? bk : bv);
  const int dr = (lane >> 4) * 4, dc = lane & 15;
#pragma unroll
  for (int m = 0; m < 8; ++m)
#pragma unroll
    for (int n = 0; n < 2; ++n) {
      const int c = ncol0 + wn * 32 + n * 16 + dc;
      const float bb = bias[c];
#pragma unroll
      for (int q = 0; q < 4; ++q) {
        const int r = arow0 + wm * 128 + m * 16 + dr + q;
        dst[(size_t)r * D_ + c] = f2bf(acc[m][n][q] + bb);
      }
    }
}

// ---------------- shared 128x128 GEMM core (m97 structure) — scores/PV ----------------
DEV void gemm_tile(const unsigned short* __restrict__ A, int lda, int arow0,
                   const unsigned short* __restrict__ B, int ldb, int brow0,
                   int ksteps, unsigned short* lsA, unsigned short* lsB,
                   f32x4 acc[4][4]) {
  const int tid  = threadIdx.x;
  const int lane = tid & 63;
  const int w    = tid >> 6;
  const int wr   = (w >> 1) * 64, wc = (w & 1) * 64;
  const int srow = tid >> 3;
  const int scol = (tid & 7) * 8;
  const int fr   = lane & 15;
  const int fk   = (lane >> 4) * 8;

  for (int ks = 0; ks < ksteps; ++ks) {
    const int k0 = ks * 64;
#pragma unroll
    for (int p = 0; p < 4; ++p) {
      gload16(A + (size_t)(arow0 + p * 32 + srow) * lda + (k0 + scol), lsA + p * 2048 + tid * 8);
      gload16(B + (size_t)(brow0 + p * 32 + srow) * ldb + (k0 + scol), lsB + p * 2048 + tid * 8);
    }
    __syncthreads();
#pragma unroll
    for (int kk = 0; kk < 2; ++kk) {
      bf16x8 af[4], bfv[4];
#pragma unroll
      for (int i = 0; i < 4; ++i) {
        af[i]  = *(const bf16x8*)(lsA + (size_t)(wr + i * 16 + fr) * 64 + kk * 32 + fk);
        bfv[i] = *(const bf16x8*)(lsB + (size_t)(wc + i * 16 + fr) * 64 + kk * 32 + fk);
      }
#pragma unroll
      for (int i = 0; i < 4; ++i)
#pragma unroll
        for (int j = 0; j < 4; ++j)
          acc[i][j] = __builtin_amdgcn_mfma_f32_16x16x32_bf16(af[i], bfv[j], acc[i][j], 0, 0, 0);
    }
    __syncthreads();
  }
}

// ---------------- V transpose: [8192,1024] -> [1024,8192] ----------------
__global__ __launch_bounds__(256) void transpose_v(const unsigned short* __restrict__ vb,
                                                   unsigned short* __restrict__ vbT) {
  __shared__ unsigned short t[64][68];
  const int bt = blockIdx.x;
  const int bo = blockIdx.y;
  const int tid = threadIdx.x;
  const int r = tid >> 4, c4 = (tid & 15) * 4;
#pragma unroll
  for (int p = 0; p < 4; ++p) {
    ushort4 v = *(const ushort4*)(vb + (size_t)(bt * 64 + p * 16 + r) * D_ + bo * 64 + c4);
    t[p * 16 + r][c4] = v.x; t[p * 16 + r][c4 + 1] = v.y;
    t[p * 16 + r][c4 + 2] = v.z; t[p * 16 + r][c4 + 3] = v.w;
  }
  __syncthreads();
#pragma unroll
  for (int p = 0; p < 4; ++p) {
    ushort4 v;
    v.x = t[c4][p * 16 + r]; v.y = t[c4 + 1][p * 16 + r];
    v.z = t[c4 + 2][p * 16 + r]; v.w = t[c4 + 3][p * 16 + r];
    *(ushort4*)(vbT + (size_t)(bo * 64 + p * 16 + r) * NTOK + bt * 64 + c4) = v;
  }
}

// ---------------- scores = Q K^T * scale, causal lower-tri tiles only ----------------
// TAIL-FOLD (r7): 544 tile-jobs (136 tri-tiles x 4 batches) on a 512-block grid.
// Blocks 0..31 take a second job (512+bid); they dispatch FIRST (LPT), so the
// makespan drops from 3 uniform rounds (~43us) to 2 (~29us).
__global__ __launch_bounds__(256) void scores_gemm(const unsigned short* __restrict__ qb,
                                                   const unsigned short* __restrict__ kb,
                                                   float* __restrict__ sbuf) {
  __shared__ unsigned short lsA[8192], lsB[8192];
  const int bid = blockIdx.x;
  const int njob = (bid < 32) ? 2 : 1;

  for (int jj = 0; jj < njob; ++jj) {
    const int job = jj == 0 ? bid : 512 + bid;   // 0..543
    const int b = job / 136;
    const int t = job - b * 136;                 // 0..135 triangular index
    int i = (int)((sqrtf(8.f * t + 1.f) - 1.f) * 0.5f);
    while ((i + 1) * (i + 2) / 2 <= t) ++i;
    while (i * (i + 1) / 2 > t) --i;
    const int j = t - i * (i + 1) / 2;           // j <= i

    f32x4 acc[4][4];
#pragma unroll
    for (int a = 0; a < 4; ++a)
#pragma unroll
      for (int c = 0; c < 4; ++c) { f32x4 z = {0.f, 0.f, 0.f, 0.f}; acc[a][c] = z; }
    const unsigned short* Ab = qb + (size_t)b * S_ * D_;
    const unsigned short* Bb = kb + (size_t)b * S_ * D_;
    gemm_tile(Ab, D_, i * 128, Bb, D_, j * 128, 16, lsA, lsB, acc);

    float* sb = sbuf + (size_t)b * S_ * S_;
    const int lane = threadIdx.x & 63, w = threadIdx.x >> 6;
    const int wr = (w >> 1) * 64, wc = (w & 1) * 64;
    const int dr = (lane >> 4) * 4, dc = lane & 15;
    constexpr float scale = 0.03125f;
#pragma unroll
    for (int fi = 0; fi < 4; ++fi)
#pragma unroll
      for (int fj = 0; fj < 4; ++fj) {
        const int kv = j * 128 + wc + fj * 16 + dc;
#pragma unroll
        for (int q = 0; q < 4; ++q) {
          const int qr = i * 128 + wr + fi * 16 + dr + q;
          float v = acc[fi][fj][q] * scale;
          if (kv > qr) v = -1e30f;
          sb[(size_t)qr * S_ + kv] = v;
        }
      }
    // LDS safe to reuse: last reads precede gemm_tile's final __syncthreads.
  }
}

// ---------------- row softmax: fp32 scores -> dense bf16 P ----------------
__global__ __launch_bounds__(256) void softmax_kernel(const float* __restrict__ sbuf,
                                                      unsigned short* __restrict__ pd) {
  const int b = blockIdx.y, q = blockIdx.x;
  const float* row = sbuf + ((size_t)b * S_ + q) * S_;
  unsigned short* prow = pd + ((size_t)b * S_ + q) * S_;
  const int len = q + 1;
  const int bound = (q & ~127) + 128;             // pv's k-extent for this row's tile
  __shared__ float buf[S_];
  __shared__ float red[4];
  const int tid = threadIdx.x, lane = tid & 63, wv = tid >> 6;

  float m = -3e38f;
  for (int k = tid; k < len; k += 256) { float s = row[k]; buf[k] = s; m = fmaxf(m, s); }
#pragma unroll
  for (int off = 32; off >= 1; off >>= 1) m = fmaxf(m, __shfl_xor(m, off));
  if (lane == 0) red[wv] = m;
  __syncthreads();
  m = fmaxf(fmaxf(red[0], red[1]), fmaxf(red[2], red[3]));
  __syncthreads();

  float l = 0.f;
  for (int k = tid; k < len; k += 256) { float e = __expf(buf[k] - m); buf[k] = e; l += e; }
#pragma unroll
  for (int off = 32; off >= 1; off >>= 1) l += __shfl_xor(l, off);
  if (lane == 0) red[wv] = l;
  __syncthreads();
  l = red[0] + red[1] + red[2] + red[3];
  const float inv = 1.f / l;
  for (int k = tid; k < bound; k += 256) {
    float p = (k < len) ? buf[k] * inv : 0.f;     // zero-fill to tile boundary for PV
    prow[k] = f2bf(p);
  }
}

// ---------------- O = P V  (causal K bound per row tile) ----------------
__global__ __launch_bounds__(256) void pv_gemm(const unsigned short* __restrict__ pd,
                                               const unsigned short* __restrict__ vbT,
                                               float* __restrict__ out) {
  __shared__ unsigned short lsA[8192], lsB[8192];
  const int it = 15 - blockIdx.x;       // longest blocks first
  const int nt = blockIdx.y;
  const int b  = blockIdx.z;
  f32x4 acc[4][4];
#pragma unroll
  for (int i = 0; i < 4; ++i)
#pragma unroll
    for (int j = 0; j < 4; ++j) { f32x4 z = {0.f, 0.f, 0.f, 0.f}; acc[i][j] = z; }
  const unsigned short* Ab = pd + (size_t)b * S_ * S_;         // dense P, lda = 2048
  const unsigned short* Bb = vbT + (size_t)b * S_;             // column offset into [1024,8192]
  gemm_tile(Ab, S_, it * 128, Bb, NTOK, nt * 128, 2 * (it + 1), lsA, lsB, acc);

  const int lane = threadIdx.x & 63, w = threadIdx.x >> 6;
  const int wr = (w >> 1) * 64, wc = (w & 1) * 64;
  const int dr = (lane >> 4) * 4, dc = lane & 15;
#pragma unroll
  for (int fi = 0; fi < 4; ++fi)
#pragma unroll
    for (int fj = 0; fj < 4; ++fj) {
      const int c = nt * 128 + wc + fj * 16 + dc;
#pragma unroll
      for (int q = 0; q < 4; ++q) {
        const int r = it * 128 + wr + fi * 16 + dr + q;
        out[((size_t)b * S_ + r) * D_ + c] = acc[fi][fj][q];
      }
    }
}

extern "C" void kernel_launch(void* const* d_in, const int* in_sizes, int n_in,
                              void* d_out, int out_size, void* d_ws, size_t ws_size,
                              hipStream_t stream) {
  (void)in_sizes; (void)n_in; (void)out_size; (void)ws_size;
  const float* x  = (const float*)d_in[0];
  const float* wq = (const float*)d_in[1];
  const float* bq = (const float*)d_in[2];
  const float* wk = (const float*)d_in[3];
  const float* bk = (const float*)d_in[4];
  const float* wv = (const float*)d_in[5];
  const float* bv = (const float*)d_in[6];
  float* out = (float*)d_out;

  char* ws = (char*)d_ws;
  unsigned short* xb = (unsigned short*)(ws + OFF_XB);
  unsigned short* wb = (unsigned short*)(ws + OFF_WB);
  unsigned short* qb = (unsigned short*)(ws + OFF_QB);
  unsigned short* kb = (unsigned short*)(ws + OFF_KB);
  unsigned short* vb = (unsigned short*)(ws + OFF_VB);
  float*          sb = (float*)(ws + OFF_SB);
  unsigned short* vbT = xb;             // xb dead after qkv; reuse (16.8MB)
  unsigned short* pd = qb;              // dense P [4][2048][2048] bf16 over qb+kb (dead after scores)

  cast_all<<<2048, 256, 0, stream>>>(x, wq, wk, wv, xb, wb);
  qkv_gemm8<<<dim3(32, 24), 512, 0, stream>>>(xb, wb, bq, bk, bv, qb, kb, vb);
  transpose_v<<<dim3(128, 16), 256, 0, stream>>>(vb, vbT);
  scores_gemm<<<512, 256, 0, stream>>>(qb, kb, sb);
  softmax_kernel<<<dim3(S_, 4), 256, 0, stream>>>(sb, pd);
  pv_gemm<<<dim3(16, 8, 4), 256, 0, stream>>>(pd, vbT, out);
}

// Round 9
// 275.611 us; speedup vs baseline: 1.0195x; 1.0195x over previous
//
#include <hip/hip_runtime.h>

#define DEV __device__ __forceinline__

typedef __bf16 bf16x8 __attribute__((ext_vector_type(8)));
typedef float  f32x4  __attribute__((ext_vector_type(4)));

// ---- constants ----
constexpr int B_ = 4, S_ = 2048, D_ = 1024;
constexpr int NTOK = B_ * S_;               // 8192
constexpr size_t XB_ELEMS = (size_t)NTOK * D_;        // 8,388,608
constexpr size_t WB_ELEMS = (size_t)3 * D_ * D_;      // 3,145,728
constexpr size_t OFF_XB = 0;
constexpr size_t OFF_WB = OFF_XB + XB_ELEMS * 2;      // 16,777,216
constexpr size_t OFF_QB = OFF_WB + WB_ELEMS * 2;      // 23,068,672
constexpr size_t OFF_KB = OFF_QB + XB_ELEMS * 2;
constexpr size_t OFF_VT = OFF_KB + XB_ELEMS * 2;      // V^T [1024][8192] bf16 (direct from qkv)
constexpr size_t OFF_SB = OFF_VT + XB_ELEMS * 2;      // 73,400,320: bf16 scores [4][2048][2048], 33.5MB
// P dense bf16 [B][S][S] reuses qb+kb (dead after scores) at OFF_QB.

DEV unsigned short f2bf(float f) {            // RNE float->bf16
  unsigned u = __float_as_uint(f);
  u += 0x7fffu + ((u >> 16) & 1u);
  return (unsigned short)(u >> 16);
}
DEV float bf2f(unsigned short u) {            // exact bf16->float
  return __uint_as_float((unsigned)u << 16);
}

DEV void gload16(const void* g, void* l) {    // 16B global->LDS direct
  __builtin_amdgcn_global_load_lds(
      (const __attribute__((address_space(1))) void*)g,
      (__attribute__((address_space(3))) void*)l, 16, 0, 0);
}

// ---------------- fused cast fp32 -> bf16 (x, wq, wk, wv in one launch) ----------------
__global__ __launch_bounds__(256) void cast_all(const float* __restrict__ x,
                                                const float* __restrict__ wq,
                                                const float* __restrict__ wk,
                                                const float* __restrict__ wv,
                                                unsigned short* __restrict__ xb,
                                                unsigned short* __restrict__ wb) {
  constexpr int NX4 = (int)(XB_ELEMS / 4);    // 2,097,152
  constexpr int NW4 = D_ * D_ / 4;            // 262,144
  constexpr int NT4 = NX4 + 3 * NW4;
  int i = blockIdx.x * 256 + threadIdx.x;
  const int stride = gridDim.x * 256;
  for (; i < NT4; i += stride) {
    const float4* s;
    ushort4* d;
    if (i < NX4) {
      s = (const float4*)x + i;
      d = (ushort4*)xb + i;
    } else {
      int j = i - NX4;
      int seg = j / NW4;
      int off = j - seg * NW4;
      const float* w = seg == 0 ? wq : (seg == 1 ? wk : wv);
      s = (const float4*)w + off;
      d = (ushort4*)wb + (size_t)seg * NW4 + off;
    }
    float4 v = *s;
    ushort4 o;
    o.x = f2bf(v.x); o.y = f2bf(v.y); o.z = f2bf(v.z); o.w = f2bf(v.w);
    *d = o;
  }
}

// ================= 8-phase 256x128 GEMM (T2+T3+T4+T5), QKV =================
// Grid 32x24 = 768 blocks = exactly 3 full rounds on 256 CUs (tail-free).
// (Measured r6: 67.1us @1507GB/s clocks, 0 bank conflicts; NT=16 plateau.)
// r9: proj==2 (V) blocks write DIRECTLY TRANSPOSED to vt[1024][8192] --
// kills the separate transpose_v kernel. Packed ushort4 (8B) stores.
__global__ __launch_bounds__(512, 2) void qkv_gemm8(
    const unsigned short* __restrict__ xb, const unsigned short* __restrict__ wb,
    const float* __restrict__ bq, const float* __restrict__ bk, const float* __restrict__ bv,
    unsigned short* __restrict__ qb, unsigned short* __restrict__ kb, unsigned short* __restrict__ vt) {
  __shared__ unsigned short lds8[49152];      // 98,304 B
  const int tid  = threadIdx.x;
  const int lane = tid & 63, wid = tid >> 6;
  const int wm = wid >> 2, wn = wid & 3;
  const int mt = blockIdx.x, nt = blockIdx.y;
  const int arow0 = mt * 256, brow0 = nt * 128;
  const int fr = lane & 15;
  const int fk16 = (lane >> 4) * 16;          // byte offset of k-chunk within 128B row
  const int srow = tid >> 3;                  // 0..63
  const int scol = (((tid & 7) * 16) ^ ((srow & 7) << 4)) >> 1;  // pre-swizzled src col

  f32x4 acc[8][2];
#pragma unroll
  for (int i = 0; i < 8; ++i)
#pragma unroll
    for (int j = 0; j < 2; ++j) { f32x4 z = {0.f, 0.f, 0.f, 0.f}; acc[i][j] = z; }

  auto stageA = [&](int buf, int T, int h) {  // half h = 128 rows of A K-tile T (2 loads)
    unsigned short* d = lds8 + buf * 24576 + h * 8192 + tid * 8;
    const unsigned short* s = xb + (size_t)(arow0 + h * 128 + srow) * D_ + T * 64 + scol;
    gload16(s, d);
    gload16(s + (size_t)64 * D_, d + 4096);
  };
  auto stageB = [&](int buf, int T, int h) {  // half h = 64 rows of B K-tile T (1 load)
    unsigned short* d = lds8 + buf * 24576 + 16384 + h * 4096 + tid * 8;
    const unsigned short* s = wb + (size_t)(brow0 + h * 64 + srow) * D_ + T * 64 + scol;
    gload16(s, d);
  };
  auto ldA = [&](int buf, int mh, int m2, int kk) -> bf16x8 {
    int row = wm * 128 + mh * 64 + m2 * 16 + fr;
    int cb = (kk * 64 + fk16) ^ ((row & 7) << 4);
    return *(const bf16x8*)(lds8 + buf * 24576 + row * 64 + (cb >> 1));
  };
  auto ldB = [&](int buf, int nh, int kk) -> bf16x8 {
    int row = wn * 32 + nh * 16 + fr;
    int cb = (kk * 64 + fk16) ^ ((row & 7) << 4);
    return *(const bf16x8*)(lds8 + buf * 24576 + 16384 + row * 64 + (cb >> 1));
  };

#define MFMA_QUAD(MH, NH, BFR)                                                     \
  do {                                                                             \
    __builtin_amdgcn_s_setprio(1);                                                 \
    _Pragma("unroll") for (int m2 = 0; m2 < 4; ++m2)                               \
    _Pragma("unroll") for (int kk = 0; kk < 2; ++kk)                               \
      acc[(MH) * 4 + m2][(NH)] = __builtin_amdgcn_mfma_f32_16x16x32_bf16(          \
          afr[m2][kk], BFR[kk], acc[(MH) * 4 + m2][(NH)], 0, 0, 0);                \
    __builtin_amdgcn_s_setprio(0);                                                 \
  } while (0)

  constexpr int NT = 16;                      // K=1024 / 64
  stageB(0, 0, 0); stageB(0, 0, 1);
  stageA(0, 0, 0); stageA(0, 0, 1);
  stageB(1, 1, 0); stageB(1, 1, 1);
  asm volatile("s_waitcnt vmcnt(2)" ::: "memory");
  __builtin_amdgcn_s_barrier();

  bf16x8 afr[4][2], bfr0[2], bfr1[2];
#pragma unroll 2
  for (int T = 0; T < NT; ++T) {
    const int cur = T & 1, nxt = cur ^ 1;
    // ---- P1 ----
#pragma unroll
    for (int kk = 0; kk < 2; ++kk) bfr0[kk] = ldB(cur, 0, kk);
#pragma unroll
    for (int m2 = 0; m2 < 4; ++m2)
#pragma unroll
      for (int kk = 0; kk < 2; ++kk) afr[m2][kk] = ldA(cur, 0, m2, kk);
    if (T + 1 < NT) stageA(nxt, T + 1, 0);
    __builtin_amdgcn_s_barrier();
    MFMA_QUAD(0, 0, bfr0);
    __builtin_amdgcn_s_barrier();
    // ---- P2 ----
#pragma unroll
    for (int kk = 0; kk < 2; ++kk) bfr1[kk] = ldB(cur, 1, kk);
    if (T + 1 < NT) stageA(nxt, T + 1, 1);
    __builtin_amdgcn_s_barrier();
    MFMA_QUAD(0, 1, bfr1);
    __builtin_amdgcn_s_barrier();
    // ---- P3 ----
#pragma unroll
    for (int m2 = 0; m2 < 4; ++m2)
#pragma unroll
      for (int kk = 0; kk < 2; ++kk) afr[m2][kk] = ldA(cur, 1, m2, kk);
    if (T + 2 < NT) stageB(cur, T + 2, 0);
    __builtin_amdgcn_s_barrier();
    MFMA_QUAD(1, 0, bfr0);
    __builtin_amdgcn_s_barrier();
    // ---- P4 ----
    if (T + 2 < NT) stageB(cur, T + 2, 1);
    __builtin_amdgcn_s_barrier();
    MFMA_QUAD(1, 1, bfr1);
    if (T + 2 < NT) {
      asm volatile("s_waitcnt vmcnt(2)" ::: "memory");
    } else {
      asm volatile("s_waitcnt vmcnt(0)" ::: "memory");
    }
    __builtin_amdgcn_s_barrier();
  }
#undef MFMA_QUAD

  // epilogue: bias + bf16 store. nt in [0,24): proj = nt/8, col tile = nt%8.
  const int proj  = nt >> 3;
  const int ncol0 = (nt & 7) * 128;
  const int dr = (lane >> 4) * 4, dc = lane & 15;
  if (proj < 2) {
    unsigned short* dst  = proj == 0 ? qb : kb;
    const float*    bias = proj == 0 ? bq : bk;
#pragma unroll
    for (int m = 0; m < 8; ++m)
#pragma unroll
      for (int n = 0; n < 2; ++n) {
        const int c = ncol0 + wn * 32 + n * 16 + dc;
        const float bb = bias[c];
#pragma unroll
        for (int q = 0; q < 4; ++q) {
          const int r = arow0 + wm * 128 + m * 16 + dr + q;
          dst[(size_t)r * D_ + c] = f2bf(acc[m][n][q] + bb);
        }
      }
  } else {
    // V: write transposed vt[c][r] = V[r][c]; 4 consecutive tokens -> ushort4 (8B)
#pragma unroll
    for (int m = 0; m < 8; ++m)
#pragma unroll
      for (int n = 0; n < 2; ++n) {
        const int c = ncol0 + wn * 32 + n * 16 + dc;       // o-dim 0..1023
        const float bb = bv[c];
        const int r = arow0 + wm * 128 + m * 16 + dr;      // token base, %4==0
        ushort4 o4;
        o4.x = f2bf(acc[m][n][0] + bb);
        o4.y = f2bf(acc[m][n][1] + bb);
        o4.z = f2bf(acc[m][n][2] + bb);
        o4.w = f2bf(acc[m][n][3] + bb);
        *(ushort4*)(vt + (size_t)c * NTOK + r) = o4;
      }
  }
}

// ---------------- shared 128x128 GEMM core (m97 structure) — scores/PV ----------------
DEV void gemm_tile(const unsigned short* __restrict__ A, int lda, int arow0,
                   const unsigned short* __restrict__ B, int ldb, int brow0,
                   int ksteps, unsigned short* lsA, unsigned short* lsB,
                   f32x4 acc[4][4]) {
  const int tid  = threadIdx.x;
  const int lane = tid & 63;
  const int w    = tid >> 6;
  const int wr   = (w >> 1) * 64, wc = (w & 1) * 64;
  const int srow = tid >> 3;
  const int scol = (tid & 7) * 8;
  const int fr   = lane & 15;
  const int fk   = (lane >> 4) * 8;

  for (int ks = 0; ks < ksteps; ++ks) {
    const int k0 = ks * 64;
#pragma unroll
    for (int p = 0; p < 4; ++p) {
      gload16(A + (size_t)(arow0 + p * 32 + srow) * lda + (k0 + scol), lsA + p * 2048 + tid * 8);
      gload16(B + (size_t)(brow0 + p * 32 + srow) * ldb + (k0 + scol), lsB + p * 2048 + tid * 8);
    }
    __syncthreads();
#pragma unroll
    for (int kk = 0; kk < 2; ++kk) {
      bf16x8 af[4], bfv[4];
#pragma unroll
      for (int i = 0; i < 4; ++i) {
        af[i]  = *(const bf16x8*)(lsA + (size_t)(wr + i * 16 + fr) * 64 + kk * 32 + fk);
        bfv[i] = *(const bf16x8*)(lsB + (size_t)(wc + i * 16 + fr) * 64 + kk * 32 + fk);
      }
#pragma unroll
      for (int i = 0; i < 4; ++i)
#pragma unroll
        for (int j = 0; j < 4; ++j)
          acc[i][j] = __builtin_amdgcn_mfma_f32_16x16x32_bf16(af[i], bfv[j], acc[i][j], 0, 0, 0);
    }
    __syncthreads();
  }
}

// ---------------- scores = Q K^T * scale (bf16 out), causal lower-tri tiles only ----------------
// TAIL-FOLD: 544 tile-jobs on a 512-block grid; blocks 0..31 take a 2nd job, first.
__global__ __launch_bounds__(256) void scores_gemm(const unsigned short* __restrict__ qb,
                                                   const unsigned short* __restrict__ kb,
                                                   unsigned short* __restrict__ sbuf) {
  __shared__ unsigned short lsA[8192], lsB[8192];
  const int bid = blockIdx.x;
  const int njob = (bid < 32) ? 2 : 1;

  for (int jj = 0; jj < njob; ++jj) {
    const int job = jj == 0 ? bid : 512 + bid;   // 0..543
    const int b = job / 136;
    const int t = job - b * 136;                 // 0..135 triangular index
    int i = (int)((sqrtf(8.f * t + 1.f) - 1.f) * 0.5f);
    while ((i + 1) * (i + 2) / 2 <= t) ++i;
    while (i * (i + 1) / 2 > t) --i;
    const int j = t - i * (i + 1) / 2;           // j <= i

    f32x4 acc[4][4];
#pragma unroll
    for (int a = 0; a < 4; ++a)
#pragma unroll
      for (int c = 0; c < 4; ++c) { f32x4 z = {0.f, 0.f, 0.f, 0.f}; acc[a][c] = z; }
    const unsigned short* Ab = qb + (size_t)b * S_ * D_;
    const unsigned short* Bb = kb + (size_t)b * S_ * D_;
    gemm_tile(Ab, D_, i * 128, Bb, D_, j * 128, 16, lsA, lsB, acc);

    unsigned short* sb = sbuf + (size_t)b * S_ * S_;
    const int lane = threadIdx.x & 63, w = threadIdx.x >> 6;
    const int wr = (w >> 1) * 64, wc = (w & 1) * 64;
    const int dr = (lane >> 4) * 4, dc = lane & 15;
    constexpr float scale = 0.03125f;
#pragma unroll
    for (int fi = 0; fi < 4; ++fi)
#pragma unroll
      for (int fj = 0; fj < 4; ++fj) {
        const int kv = j * 128 + wc + fj * 16 + dc;
#pragma unroll
        for (int q = 0; q < 4; ++q) {
          const int qr = i * 128 + wr + fi * 16 + dr + q;
          float v = acc[fi][fj][q] * scale;
          if (kv > qr) v = -1e30f;
          sb[(size_t)qr * S_ + kv] = f2bf(v);
        }
      }
    // LDS safe to reuse: last reads precede gemm_tile's final __syncthreads.
  }
}

// ---------------- row softmax: bf16 scores -> dense bf16 P ----------------
__global__ __launch_bounds__(256) void softmax_kernel(const unsigned short* __restrict__ sbuf,
                                                      unsigned short* __restrict__ pd) {
  const int b = blockIdx.y, q = blockIdx.x;
  const unsigned short* row = sbuf + ((size_t)b * S_ + q) * S_;
  unsigned short* prow = pd + ((size_t)b * S_ + q) * S_;
  const int len = q + 1;
  const int bound = (q & ~127) + 128;             // pv's k-extent for this row's tile
  __shared__ float buf[S_];
  __shared__ float red[4];
  const int tid = threadIdx.x, lane = tid & 63, wv = tid >> 6;

  float m = -3e38f;
  for (int k = tid; k < len; k += 256) { float s = bf2f(row[k]); buf[k] = s; m = fmaxf(m, s); }
#pragma unroll
  for (int off = 32; off >= 1; off >>= 1) m = fmaxf(m, __shfl_xor(m, off));
  if (lane == 0) red[wv] = m;
  __syncthreads();
  m = fmaxf(fmaxf(red[0], red[1]), fmaxf(red[2], red[3]));
  __syncthreads();

  float l = 0.f;
  for (int k = tid; k < len; k += 256) { float e = __expf(buf[k] - m); buf[k] = e; l += e; }
#pragma unroll
  for (int off = 32; off >= 1; off >>= 1) l += __shfl_xor(l, off);
  if (lane == 0) red[wv] = l;
  __syncthreads();
  l = red[0] + red[1] + red[2] + red[3];
  const float inv = 1.f / l;
  for (int k = tid; k < bound; k += 256) {
    float p = (k < len) ? buf[k] * inv : 0.f;     // zero-fill to tile boundary for PV
    prow[k] = f2bf(p);
  }
}

// ---------------- O = P V  (causal K bound per row tile) ----------------
__global__ __launch_bounds__(256) void pv_gemm(const unsigned short* __restrict__ pd,
                                               const unsigned short* __restrict__ vt,
                                               float* __restrict__ out) {
  __shared__ unsigned short lsA[8192], lsB[8192];
  const int it = 15 - blockIdx.x;       // longest blocks first
  const int nt = blockIdx.y;
  const int b  = blockIdx.z;
  f32x4 acc[4][4];
#pragma unroll
  for (int i = 0; i < 4; ++i)
#pragma unroll
    for (int j = 0; j < 4; ++j) { f32x4 z = {0.f, 0.f, 0.f, 0.f}; acc[i][j] = z; }
  const unsigned short* Ab = pd + (size_t)b * S_ * S_;         // dense P, lda = 2048
  const unsigned short* Bb = vt + (size_t)b * S_;              // column offset into [1024][8192]
  gemm_tile(Ab, S_, it * 128, Bb, NTOK, nt * 128, 2 * (it + 1), lsA, lsB, acc);

  const int lane = threadIdx.x & 63, w = threadIdx.x >> 6;
  const int wr = (w >> 1) * 64, wc = (w & 1) * 64;
  const int dr = (lane >> 4) * 4, dc = lane & 15;
#pragma unroll
  for (int fi = 0; fi < 4; ++fi)
#pragma unroll
    for (int fj = 0; fj < 4; ++fj) {
      const int c = nt * 128 + wc + fj * 16 + dc;
#pragma unroll
      for (int q = 0; q < 4; ++q) {
        const int r = it * 128 + wr + fi * 16 + dr + q;
        out[((size_t)b * S_ + r) * D_ + c] = acc[fi][fj][q];
      }
    }
}

extern "C" void kernel_launch(void* const* d_in, const int* in_sizes, int n_in,
                              void* d_out, int out_size, void* d_ws, size_t ws_size,
                              hipStream_t stream) {
  (void)in_sizes; (void)n_in; (void)out_size; (void)ws_size;
  const float* x  = (const float*)d_in[0];
  const float* wq = (const float*)d_in[1];
  const float* bq = (const float*)d_in[2];
  const float* wk = (const float*)d_in[3];
  const float* bk = (const float*)d_in[4];
  const float* wv = (const float*)d_in[5];
  const float* bv = (const float*)d_in[6];
  float* out = (float*)d_out;

  char* ws = (char*)d_ws;
  unsigned short* xb = (unsigned short*)(ws + OFF_XB);
  unsigned short* wb = (unsigned short*)(ws + OFF_WB);
  unsigned short* qb = (unsigned short*)(ws + OFF_QB);
  unsigned short* kb = (unsigned short*)(ws + OFF_KB);
  unsigned short* vt = (unsigned short*)(ws + OFF_VT);  // V^T [1024][8192], written by qkv
  unsigned short* sb = (unsigned short*)(ws + OFF_SB);  // bf16 scores
  unsigned short* pd = qb;              // dense P [4][2048][2048] bf16 over qb+kb (dead after scores)

  cast_all<<<2048, 256, 0, stream>>>(x, wq, wk, wv, xb, wb);
  qkv_gemm8<<<dim3(32, 24), 512, 0, stream>>>(xb, wb, bq, bk, bv, qb, kb, vt);
  scores_gemm<<<512, 256, 0, stream>>>(qb, kb, sb);
  softmax_kernel<<<dim3(S_, 4), 256, 0, stream>>>(sb, pd);
  pv_gemm<<<dim3(16, 8, 4), 256, 0, stream>>>(pd, vt, out);
}